// Round 19
// baseline (137.938 us; speedup 1.0000x reference)
//
#include <hip/hip_runtime.h>
#include <hip/hip_bf16.h>

#define E_TOT 500000
#define N_NODES 100000
#define NUNITS_H 3125   // 32-row units per half (3125*32 = 100000)
#define SRD 128         // strip-groups per (half, colhalf)

typedef __attribute__((ext_vector_type(16))) float f32x16;
typedef __attribute__((ext_vector_type(8))) short short8;
typedef __attribute__((ext_vector_type(4))) float f32x4;

__device__ __forceinline__ unsigned short f2bf(float f) {
  union { float f; unsigned u; } x; x.f = f;
  unsigned r = x.u + 0x7fffu + ((x.u >> 16) & 1u);
  return (unsigned short)(r >> 16);
}

__device__ __forceinline__ float bf2f(unsigned short s) {
  union { unsigned u; float f; } x; x.u = ((unsigned)s) << 16;
  return x.f;
}

__device__ __forceinline__ short cvt1(float f) {
  __hip_bfloat16 h = __float2bfloat16(f);  // RNE; pairs fuse to v_cvt_pk
  union { __hip_bfloat16 h; short s; } u; u.h = h;
  return u.s;
}

__device__ __forceinline__ void gl_lds16(const void* g, void* l) {
  __builtin_amdgcn_global_load_lds(
      (const __attribute__((address_space(1))) void*)g,
      (__attribute__((address_space(3))) void*)l, 16, 0, 0);
}

// w1 (f32 [256][512]) -> w1r2 bf16 [half][kseg=0..31][n=0..255][j=0..7]
__global__ void k_repack_w1h(const float* __restrict__ w1,
                             unsigned short* __restrict__ w1r2) {
  int o = blockIdx.x * 256 + threadIdx.x;  // 131072 total
  int half = o >> 16;
  int kb = (o >> 11) & 31;
  int n = (o >> 3) & 255;
  int j = o & 7;
  w1r2[o] = f2bf(w1[n * 512 + half * 256 + kb * 8 + j]);
}

// U'[n] = zsrc[n] @ W1s^T + b1 (half 0) ; V[n] = zdst[n] @ W1d^T (half 1)
// v18: TWO independent 4-wave blocks per CU (N split in col-halves), so
// blocks overlap each other's stall phases. A via swizzled gl_lds double
// buffer; B slice in AGPRs; counted vmcnt; 2 barriers/unit; full-line stores.
// A is staged twice chip-wide (per col-half) but z is L3-resident.
__global__ __launch_bounds__(256, 2) void k_node_gemm(
    const float* __restrict__ zsrc, const float* __restrict__ zdst,
    const unsigned short* __restrict__ w1r2, const float* __restrict__ b1,
    unsigned short* __restrict__ Uo, unsigned short* __restrict__ Vo) {
  // 2 x 32KB A f32 double-buffer + 8KB Ct = 72KB -> 2 blocks/CU
  __shared__ __align__(16) char smem[73728];
  unsigned short* Ct = (unsigned short*)(smem + 65536);

  const int bid = blockIdx.x;          // 512 blocks
  const int half = bid >> 8;           // 0/1
  const int ch = (bid >> 7) & 1;       // col-half: cols ch*128..ch*128+127
  const int bg = bid & 127;            // strip group
  const float* Z = half ? zdst : zsrc;
  unsigned short* O = half ? Vo : Uo;

  const unsigned tid = threadIdx.x;
  const unsigned l = tid & 63u;
  const unsigned wv = tid >> 6;   // wave 0..3 -> cols ch*128 + wv*32 + l31
  const unsigned l31 = l & 31u;
  const unsigned hi = l >> 5;
  const unsigned xr = (l31 & 7u) << 4;  // read-side XOR swizzle

  // ---- B fragments: 16 x short8 for this wave's 32 cols (parked in AGPRs) --
  short8 brg[16];
  {
    const unsigned short* bb = w1r2 + (unsigned)half * 65536u;
    unsigned col = (unsigned)ch * 128u + wv * 32u + l31;
#pragma unroll
    for (int k = 0; k < 16; ++k) {
      unsigned ks = (unsigned)k * 2u + hi;
      brg[k] = *(const short8*)(bb + (ks * 256u + col) * 8u);
      asm volatile("" : "+v"(brg[k]));  // opacity: no re-materialization
    }
  }

  const float bi = half ? 0.f : b1[(unsigned)ch * 128u + wv * 32u + l31];

  // Stage unit uu (32 rows x 1KB f32) into buffer bf (0/1); wave stages rows
  // wv*8+q. Source pre-swizzled: LDS[row*1024+b] = global[row*1024+(b^((row&7)<<4))]
#define STAGE(uu, bf)                                                     \
  {                                                                       \
    int uc_ = (uu); if (uc_ >= NUNITS_H) uc_ = NUNITS_H - 1;              \
    const char* src_ = (const char*)(Z + (long)uc_ * 32 * 256);           \
    char* dst_ = smem + (unsigned)(bf)*32768u;                            \
    _Pragma("unroll") for (int q = 0; q < 8; ++q) {                       \
      unsigned row_ = wv * 8u + (unsigned)q;                              \
      unsigned off_ = row_ * 1024u;                                       \
      unsigned so_ = off_ + ((l * 16u) ^ ((row_ & 7u) << 4));             \
      gl_lds16(src_ + so_, dst_ + off_);                                  \
    }                                                                     \
  }

  int u = bg;
  int cur = 0;
  STAGE(u, 0);
  asm volatile("s_waitcnt vmcnt(0)" ::: "memory");
  __builtin_amdgcn_s_barrier();

  for (; u < NUNITS_H; u += SRD) {
    STAGE(u + SRD, cur ^ 1);            // 8 ops/wave, stays in flight
    __builtin_amdgcn_sched_barrier(0);
    // younger-than-S(u): stores(prev) 2 + S(u+SRD) 8 = 10; vmcnt(8) is
    // strictly safe at every iter and keeps all of S(u+SRD) outstanding.
    asm volatile("s_waitcnt vmcnt(8)" ::: "memory");
    __builtin_amdgcn_s_barrier();

    const char* Ab = smem + (unsigned)cur * 32768u;
    f32x16 acc = {0.f, 0.f, 0.f, 0.f, 0.f, 0.f, 0.f, 0.f,
                  0.f, 0.f, 0.f, 0.f, 0.f, 0.f, 0.f, 0.f};
#pragma unroll
    for (int kk = 0; kk < 16; ++kk) {
      unsigned c0 = (unsigned)kk * 64u + hi * 32u;
      f32x4 a0 = *(const f32x4*)(Ab + l31 * 1024u + (c0 ^ xr));
      f32x4 a1 = *(const f32x4*)(Ab + l31 * 1024u + ((c0 + 16u) ^ xr));
      short8 af;
      af[0] = cvt1(a0.x); af[1] = cvt1(a0.y);
      af[2] = cvt1(a0.z); af[3] = cvt1(a0.w);
      af[4] = cvt1(a1.x); af[5] = cvt1(a1.y);
      af[6] = cvt1(a1.z); af[7] = cvt1(a1.w);
      acc = __builtin_amdgcn_mfma_f32_32x32x16_bf16(af, brg[kk], acc, 0, 0, 0);
    }

    // C tile (32 x 128 bf16) -> LDS; drain lgkm only
#pragma unroll
    for (int r = 0; r < 16; ++r) {
      unsigned row32 = (unsigned)((r & 3) + 8 * (r >> 2)) + 4u * hi;
      Ct[row32 * 128u + wv * 32u + l31] = f2bf(acc[r] + bi);
    }
    asm volatile("s_waitcnt lgkmcnt(0)" ::: "memory");
    __builtin_amdgcn_s_barrier();

    // stores: 256B contiguous per row (two full 128B lines), no row guard
    // (3125*32 == 100000 exactly)
    {
      unsigned short* ob = O + (long)u * 32 * 256 + (unsigned)ch * 128u;
#pragma unroll
      for (int p = 0; p < 2; ++p) {
        unsigned s = (unsigned)p * 256u + tid;
        unsigned row = s >> 4;
        unsigned seg = s & 15u;
        short8 vv = *(const short8*)&Ct[row * 128u + seg * 8u];
        *(short8*)(ob + (long)row * 256 + seg * 8u) = vv;
      }
    }
    cur ^= 1;
  }
#undef STAGE
}

// per edge: out = sigmoid( w2 . relu(U'[row] + V[col]) + b2 )
// 3-stage pipeline: idx(e+2) || rows(e+1) || compute(e)
#define EK_ITER 16
__global__ __launch_bounds__(256, 6) void k_edge(
    const unsigned short* __restrict__ U, const unsigned short* __restrict__ V,
    const int* __restrict__ eli, const float* __restrict__ w2,
    const float* __restrict__ b2, float* __restrict__ out) {
  const int tid = threadIdx.x;
  const int g = tid >> 4;
  const int j = tid & 15;
  float w2v[16];
#pragma unroll
  for (int q = 0; q < 8; ++q) {
    w2v[q] = w2[8 * j + q];
    w2v[8 + q] = w2[128 + 8 * j + q];
  }
  const float b2v = b2[0];
  const long base = (long)blockIdx.x * (16 * EK_ITER) + g;

#define CLAMP_E(k) \
  (((base + 16 * (k)) < E_TOT) ? (base + 16 * (k)) : (long)(E_TOT - 1))

  long eP = CLAMP_E(0);
  int rA = eli[eP], cA = eli[E_TOT + eP];
  long eQ = CLAMP_E(1);
  int rB = eli[eQ], cB = eli[E_TOT + eQ];
  short8 uA0 = *(const short8*)(U + (long)rA * 256 + 8 * j);
  short8 uA1 = *(const short8*)(U + (long)rA * 256 + 128 + 8 * j);
  short8 vA0 = *(const short8*)(V + (long)cA * 256 + 8 * j);
  short8 vA1 = *(const short8*)(V + (long)cA * 256 + 128 + 8 * j);
  short8 uB0, uB1, vB0, vB1;

#pragma unroll
  for (int it2 = 0; it2 < EK_ITER / 2; ++it2) {
    {
      long eN = CLAMP_E(2 * it2 + 2);
      int rN = eli[eN], cN = eli[E_TOT + eN];
      uB0 = *(const short8*)(U + (long)rB * 256 + 8 * j);
      uB1 = *(const short8*)(U + (long)rB * 256 + 128 + 8 * j);
      vB0 = *(const short8*)(V + (long)cB * 256 + 8 * j);
      vB1 = *(const short8*)(V + (long)cB * 256 + 128 + 8 * j);
      rB = rN; cB = cN;
      float p = 0.f;
#pragma unroll
      for (int q = 0; q < 8; ++q) {
        float a0 = bf2f((unsigned short)uA0[q]) + bf2f((unsigned short)vA0[q]);
        float a1 = bf2f((unsigned short)uA1[q]) + bf2f((unsigned short)vA1[q]);
        p = fmaf(fmaxf(a0, 0.f), w2v[q], p);
        p = fmaf(fmaxf(a1, 0.f), w2v[8 + q], p);
      }
      p += __shfl_xor(p, 1);
      p += __shfl_xor(p, 2);
      p += __shfl_xor(p, 4);
      p += __shfl_xor(p, 8);
      long e = base + 16 * (2 * it2);
      if (j == 0 && e < E_TOT) out[e] = 1.f / (1.f + __expf(-(p + b2v)));
    }
    {
      long eN = CLAMP_E(2 * it2 + 3);
      int rN = eli[eN], cN = eli[E_TOT + eN];
      uA0 = *(const short8*)(U + (long)rB * 256 + 8 * j);
      uA1 = *(const short8*)(U + (long)rB * 256 + 128 + 8 * j);
      vA0 = *(const short8*)(V + (long)cB * 256 + 8 * j);
      vA1 = *(const short8*)(V + (long)cB * 256 + 128 + 8 * j);
      rB = rN; cB = cN;
      float p = 0.f;
#pragma unroll
      for (int q = 0; q < 8; ++q) {
        float a0 = bf2f((unsigned short)uB0[q]) + bf2f((unsigned short)vB0[q]);
        float a1 = bf2f((unsigned short)uB1[q]) + bf2f((unsigned short)vB1[q]);
        p = fmaf(fmaxf(a0, 0.f), w2v[q], p);
        p = fmaf(fmaxf(a1, 0.f), w2v[8 + q], p);
      }
      p += __shfl_xor(p, 1);
      p += __shfl_xor(p, 2);
      p += __shfl_xor(p, 4);
      p += __shfl_xor(p, 8);
      long e = base + 16 * (2 * it2 + 1);
      if (j == 0 && e < E_TOT) out[e] = 1.f / (1.f + __expf(-(p + b2v)));
    }
  }
#undef CLAMP_E
}

extern "C" void kernel_launch(void* const* d_in, const int* in_sizes, int n_in,
                              void* d_out, int out_size, void* d_ws,
                              size_t ws_size, hipStream_t stream) {
  const float* zsrc = (const float*)d_in[0];
  const float* zdst = (const float*)d_in[1];
  const int* eli = (const int*)d_in[2];
  const float* w1 = (const float*)d_in[3];
  const float* b1 = (const float*)d_in[4];
  const float* w2 = (const float*)d_in[5];
  const float* b2 = (const float*)d_in[6];
  float* out = (float*)d_out;

  const size_t uv_bytes = (size_t)N_NODES * 256 * 2;  // 51.2 MB each
  unsigned short* U = (unsigned short*)d_ws;
  unsigned short* V = (unsigned short*)((char*)d_ws + uv_bytes);
  unsigned short* w1r2 = (unsigned short*)((char*)d_ws + 2 * uv_bytes);

  k_repack_w1h<<<512, 256, 0, stream>>>(w1, w1r2);
  k_node_gemm<<<512, 256, 0, stream>>>(zsrc, zdst, w1r2, b1, U, V);
  int nbe = (E_TOT + 16 * EK_ITER - 1) / (16 * EK_ITER);
  k_edge<<<nbe, 256, 0, stream>>>(U, V, eli, w2, b2, out);
}